// Round 2
// baseline (164096.033 us; speedup 1.0000x reference)
//
#include <hip/hip_runtime.h>
#include <math.h>

#define TT 2048
#define II 64
#define HH 512
#define LL 5
#define RING 8
#define BPL 32               // blocks per layer
#define NBLK (LL * BPL)      // 160
#define WPB 16               // waves per block

__device__ __forceinline__ float wave_sum(float v) {
#pragma unroll
  for (int m = 32; m > 0; m >>= 1) v += __shfl_xor(v, m, 64);
  return v;
}

__device__ __forceinline__ float wave_max(float v) {
#pragma unroll
  for (int m = 32; m > 0; m >>= 1) v = fmaxf(v, __shfl_xor(v, m, 64));
  return v;
}

__device__ __forceinline__ float sigmoidf_(float v) {
  return 1.0f / (1.0f + expf(-v));
}

__device__ __forceinline__ unsigned ld_cnt(unsigned* p) {
  return __hip_atomic_load(p, __ATOMIC_RELAXED, __HIP_MEMORY_SCOPE_AGENT);
}

// Bounded spin; fetch_max escape degrades residency failure to wrong-answer
// instead of hang.
__device__ __forceinline__ void wait_ge(unsigned* p, unsigned v) {
  long spins = 0;
  while (ld_cnt(p) < v) {
    if (++spins > 8000000L) {
      __hip_atomic_fetch_max(p, v, __ATOMIC_RELAXED, __HIP_MEMORY_SCOPE_AGENT);
      break;
    }
  }
}

// Monotone full-grid barrier (used only for the 3 readout phase transitions).
__device__ __forceinline__ void grid_barrier(unsigned* arrive, unsigned* gen, unsigned idx) {
  __syncthreads();
  if (threadIdx.x == 0) {
    __threadfence();
    unsigned target = (unsigned)NBLK * (idx + 1u);
    unsigned prev = __hip_atomic_fetch_add(arrive, 1u, __ATOMIC_RELAXED, __HIP_MEMORY_SCOPE_AGENT);
    if (prev + 1u == target) {
      __hip_atomic_store(gen, idx + 1u, __ATOMIC_RELAXED, __HIP_MEMORY_SCOPE_AGENT);
    } else {
      wait_ge(gen, idx + 1u);
    }
  }
  __syncthreads();
  __threadfence();
}

extern "C" __global__ void __launch_bounds__(1024, 4) lstm_pipe(
    const float* __restrict__ x,
    const float* __restrict__ w_ih0, const float* __restrict__ w_hh0,
    const float* __restrict__ b_ih0, const float* __restrict__ b_hh0,
    const float* __restrict__ w_ih, const float* __restrict__ w_hh,
    const float* __restrict__ b_ih, const float* __restrict__ b_hh,
    const float* __restrict__ w_lin, const float* __restrict__ b_lin,
    float* __restrict__ out, float* __restrict__ ws) {
  // counters in first 1024 B of ws:
  //   arr[l]  at cnt[l*16]       (l = 0..4, 64 B apart)
  //   gen[l]  at cnt[80 + l*16]
  //   garr    at cnt[160], ggen at cnt[176]
  unsigned* cnt = (unsigned*)ws;
  float* data = ws + 256;  // byte offset 1024
  float* h_ring = data;                          // LL*RING*HH
  float* h4 = h_ring + LL * RING * HH;           // TT*HH
  float* h4T = h4 + (size_t)TT * HH;             // HH*TT
  float* scores = h4T + (size_t)HH * TT;         // TT
  float* pbuf = scores + TT;                     // TT
  float* red = pbuf + TT;                        // 1

  const int b = blockIdx.x;
  const int tid = threadIdx.x;
  const int wv = tid >> 6;
  const int lane = tid & 63;
  const int l = b / BPL;
  const int q = b % BPL;
  const int j = q * WPB + wv;  // h-output index owned by this wave

  unsigned* arr_l = cnt + l * 16;
  unsigned* gen_l = cnt + 80 + l * 16;
  unsigned* gen_lm1 = cnt + 80 + (l - 1) * 16;  // used only when l > 0
  unsigned* gen_lp1 = cnt + 80 + (l + 1) * 16;  // used only when l < LL-1
  unsigned* garr = cnt + 160;
  unsigned* ggen = cnt + 176;

  // ---- pin weights in registers (uniform layout for all layers) ----
  float whh[4][8], wih[4][8], bias[4];
  const float* WHH = (l == 0) ? w_hh0 : (w_hh + (size_t)(l - 1) * 4 * HH * HH);
#pragma unroll
  for (int g = 0; g < 4; ++g) {
    const int row = g * HH + j;
    const float4* p = (const float4*)(WHH + (size_t)row * HH + lane * 8);
    float4 a = p[0], d = p[1];
    whh[g][0] = a.x; whh[g][1] = a.y; whh[g][2] = a.z; whh[g][3] = a.w;
    whh[g][4] = d.x; whh[g][5] = d.y; whh[g][6] = d.z; whh[g][7] = d.w;
  }
  if (l == 0) {
#pragma unroll
    for (int g = 0; g < 4; ++g) {
      const int row = g * HH + j;
      wih[g][0] = w_ih0[(size_t)row * II + lane];
#pragma unroll
      for (int m = 1; m < 8; ++m) wih[g][m] = 0.0f;
      bias[g] = b_ih0[row] + b_hh0[row];
    }
  } else {
    const float* WIH = w_ih + (size_t)(l - 1) * 4 * HH * HH;
    const float* BIH = b_ih + (size_t)(l - 1) * 4 * HH;
    const float* BHH = b_hh + (size_t)(l - 1) * 4 * HH;
#pragma unroll
    for (int g = 0; g < 4; ++g) {
      const int row = g * HH + j;
      const float4* p = (const float4*)(WIH + (size_t)row * HH + lane * 8);
      float4 a = p[0], d = p[1];
      wih[g][0] = a.x; wih[g][1] = a.y; wih[g][2] = a.z; wih[g][3] = a.w;
      wih[g][4] = d.x; wih[g][5] = d.y; wih[g][6] = d.z; wih[g][7] = d.w;
      bias[g] = BIH[row] + BHH[row];
    }
  }

  const float* own_rd = h_ring + (size_t)l * RING * HH + lane * 8;
  const float* prev_rd = h_ring + (size_t)(l - 1) * RING * HH + lane * 8;
  float* own_wr = h_ring + (size_t)l * RING * HH + j;

  float c = 0.0f;

  // ---- recurrence: per-layer barriers + ring back-pressure ----
  for (int t = 0; t < TT; ++t) {
    if (tid == 0) {
      if (t > 0) wait_ge(gen_l, (unsigned)t);                          // own h_{t-1}
      if (l > 0) wait_ge(gen_lm1, (unsigned)(t + 1));                  // input ready
      if (l < LL - 1 && t >= RING) wait_ge(gen_lp1, (unsigned)(t - RING + 1));  // ring slot free
    }
    __syncthreads();
    __threadfence();  // acquire: every wave invalidates before reading h

    float hp[8];
    if (t > 0) {
      const float4* p = (const float4*)(own_rd + (size_t)((t - 1) & (RING - 1)) * HH);
      float4 a = p[0], d = p[1];
      hp[0] = a.x; hp[1] = a.y; hp[2] = a.z; hp[3] = a.w;
      hp[4] = d.x; hp[5] = d.y; hp[6] = d.z; hp[7] = d.w;
    } else {
#pragma unroll
      for (int m = 0; m < 8; ++m) hp[m] = 0.0f;
    }
    float xin[8];
    if (l == 0) {
      xin[0] = x[(size_t)t * II + lane];
#pragma unroll
      for (int m = 1; m < 8; ++m) xin[m] = 0.0f;
    } else {
      const float4* p = (const float4*)(prev_rd + (size_t)(t & (RING - 1)) * HH);
      float4 a = p[0], d = p[1];
      xin[0] = a.x; xin[1] = a.y; xin[2] = a.z; xin[3] = a.w;
      xin[4] = d.x; xin[5] = d.y; xin[6] = d.z; xin[7] = d.w;
    }

    float ai = 0.0f, af = 0.0f, ag = 0.0f, ao = 0.0f;
#pragma unroll
    for (int m = 0; m < 8; ++m) {
      ai = fmaf(whh[0][m], hp[m], ai);
      af = fmaf(whh[1][m], hp[m], af);
      ag = fmaf(whh[2][m], hp[m], ag);
      ao = fmaf(whh[3][m], hp[m], ao);
    }
#pragma unroll
    for (int m = 0; m < 8; ++m) {
      ai = fmaf(wih[0][m], xin[m], ai);
      af = fmaf(wih[1][m], xin[m], af);
      ag = fmaf(wih[2][m], xin[m], ag);
      ao = fmaf(wih[3][m], xin[m], ao);
    }
    ai = wave_sum(ai); af = wave_sum(af); ag = wave_sum(ag); ao = wave_sum(ao);
    float gi = sigmoidf_(ai + bias[0]);
    float gf = sigmoidf_(af + bias[1]);
    float gg = tanhf(ag + bias[2]);
    float go = sigmoidf_(ao + bias[3]);
    c = gf * c + gi * gg;
    float h = go * tanhf(c);
    if (lane == 0) {
      own_wr[(size_t)(t & (RING - 1)) * HH] = h;
      if (l == LL - 1) {
        h4[(size_t)t * HH + j] = h;
        h4T[(size_t)j * TT + t] = h;
      }
    }
    __threadfence();  // release: h visible before arrival
    __syncthreads();
    if (tid == 0) {
      unsigned prev = __hip_atomic_fetch_add(arr_l, 1u, __ATOMIC_RELAXED, __HIP_MEMORY_SCOPE_AGENT);
      if (prev + 1u == (unsigned)BPL * (unsigned)(t + 1)) {
        __hip_atomic_store(gen_l, (unsigned)(t + 1), __ATOMIC_RELAXED, __HIP_MEMORY_SCOPE_AGENT);
      }
    }
  }

  grid_barrier(garr, ggen, 0u);

  // ---- phase A: scores[t] = tanh(h4[t] . w_lin + b_lin) ----
  {
    const int gw = b * WPB + wv;
    if (gw < TT) {
      const int t = gw;
      const float4* hp4 = (const float4*)(h4 + (size_t)t * HH + lane * 8);
      const float4* wl4 = (const float4*)(w_lin + lane * 8);
      float4 a = hp4[0], d = hp4[1], wa = wl4[0], wd = wl4[1];
      float acc = 0.0f;
      acc = fmaf(a.x, wa.x, acc); acc = fmaf(a.y, wa.y, acc);
      acc = fmaf(a.z, wa.z, acc); acc = fmaf(a.w, wa.w, acc);
      acc = fmaf(d.x, wd.x, acc); acc = fmaf(d.y, wd.y, acc);
      acc = fmaf(d.z, wd.z, acc); acc = fmaf(d.w, wd.w, acc);
      acc = wave_sum(acc);
      float sc = tanhf(acc + b_lin[0]);
      if (lane == 0) scores[t] = sc;
    }
  }
  grid_barrier(garr, ggen, 1u);

  // ---- phase B: softmax over time (block 0 only) ----
  __shared__ float sbuf[20];
  if (b == 0) {
    float s0 = scores[tid];
    float s1 = scores[tid + 1024];
    float m = fmaxf(s0, s1);
    m = wave_max(m);
    if (lane == 0) sbuf[wv] = m;
    __syncthreads();
    if (tid == 0) {
      float M = sbuf[0];
      for (int k = 1; k < 16; ++k) M = fmaxf(M, sbuf[k]);
      sbuf[16] = M;
    }
    __syncthreads();
    float M = sbuf[16];
    float p0 = expf(s0 - M), p1 = expf(s1 - M);
    pbuf[tid] = p0;
    pbuf[tid + 1024] = p1;
    float ssum = wave_sum(p0 + p1);
    __syncthreads();
    if (lane == 0) sbuf[wv] = ssum;
    __syncthreads();
    if (tid == 0) {
      float S = 0.0f;
      for (int k = 0; k < 16; ++k) S += sbuf[k];
      red[0] = 1.0f / ((float)TT * S);
    }
  }
  grid_barrier(garr, ggen, 2u);

  // ---- phase C: out[j] = scale * sum_t p_t * h4T[j][t] ----
  {
    const int gw = b * WPB + wv;
    if (gw < HH) {
      const int jj = gw;
      const float scale = red[0];
      const float* hr = h4T + (size_t)jj * TT + lane * 32;
      const float* pr = pbuf + lane * 32;
      float acc = 0.0f;
#pragma unroll
      for (int m = 0; m < 32; ++m) acc = fmaf(hr[m], pr[m], acc);
      acc = wave_sum(acc);
      if (lane == 0) out[jj] = scale * acc;
    }
  }
}

extern "C" void kernel_launch(void* const* d_in, const int* in_sizes, int n_in,
                              void* d_out, int out_size, void* d_ws, size_t ws_size,
                              hipStream_t stream) {
  hipMemsetAsync(d_ws, 0, 1024, stream);  // zero all sync counters
  lstm_pipe<<<dim3(NBLK), dim3(1024), 0, stream>>>(
      (const float*)d_in[0],
      (const float*)d_in[1], (const float*)d_in[2],
      (const float*)d_in[3], (const float*)d_in[4],
      (const float*)d_in[5], (const float*)d_in[6],
      (const float*)d_in[7], (const float*)d_in[8],
      (const float*)d_in[9], (const float*)d_in[10],
      (float*)d_out, (float*)d_ws);
}

// Round 3
// 8911.244 us; speedup vs baseline: 18.4145x; 18.4145x over previous
//
#include <hip/hip_runtime.h>
#include <math.h>

#define TT 2048
#define II 64
#define HH 512
#define LL 5
#define RING 8
#define BPL 32               // blocks per layer
#define NBLK (LL * BPL)      // 160
#define WPB 16               // waves per block

__device__ __forceinline__ float wave_sum(float v) {
#pragma unroll
  for (int m = 32; m > 0; m >>= 1) v += __shfl_xor(v, m, 64);
  return v;
}

__device__ __forceinline__ float wave_max(float v) {
#pragma unroll
  for (int m = 32; m > 0; m >>= 1) v = fmaxf(v, __shfl_xor(v, m, 64));
  return v;
}

__device__ __forceinline__ float sigmoidf_(float v) {
  return 1.0f / (1.0f + expf(-v));
}

__device__ __forceinline__ unsigned ld_cnt(const unsigned* p) {
  return __hip_atomic_load((unsigned*)p, __ATOMIC_RELAXED, __HIP_MEMORY_SCOPE_AGENT);
}

// Bounded spin; fetch_max escape degrades residency failure to wrong-answer
// instead of hang.
__device__ __forceinline__ void wait_ge(unsigned* p, unsigned v) {
  long spins = 0;
  while (ld_cnt(p) < v) {
    if (++spins > 8000000L) {
      __hip_atomic_fetch_max(p, v, __ATOMIC_RELAXED, __HIP_MEMORY_SCOPE_AGENT);
      break;
    }
  }
}

// Coherent 4B exchange: relaxed agent-scope atomics are HW-coherent at the
// device coherence point (no L1/L2 staleness), so no fences are needed.
__device__ __forceinline__ float ld_coh(const float* p) {
  return __hip_atomic_load((float*)p, __ATOMIC_RELAXED, __HIP_MEMORY_SCOPE_AGENT);
}
__device__ __forceinline__ void st_coh(float* p, float v) {
  __hip_atomic_store(p, v, __ATOMIC_RELAXED, __HIP_MEMORY_SCOPE_AGENT);
}

// Monotone full-grid barrier — readout phase transitions only (3 uses).
// thread0 does the expensive agent fences; trailing all-thread fence is the
// acquire for every wave's subsequent plain loads.
__device__ __forceinline__ void grid_barrier(unsigned* arrive, unsigned* gen, unsigned idx) {
  __syncthreads();
  if (threadIdx.x == 0) {
    __threadfence();  // release: wbl2 — flush this XCD's dirty lines
    unsigned target = (unsigned)NBLK * (idx + 1u);
    unsigned prev = __hip_atomic_fetch_add(arrive, 1u, __ATOMIC_RELAXED, __HIP_MEMORY_SCOPE_AGENT);
    if (prev + 1u == target) {
      __hip_atomic_store(gen, idx + 1u, __ATOMIC_RELAXED, __HIP_MEMORY_SCOPE_AGENT);
    } else {
      wait_ge(gen, idx + 1u);
    }
    __threadfence();  // acquire: inv
  }
  __syncthreads();
}

extern "C" __global__ void __launch_bounds__(1024, 4) lstm_pipe(
    const float* __restrict__ x,
    const float* __restrict__ w_ih0, const float* __restrict__ w_hh0,
    const float* __restrict__ b_ih0, const float* __restrict__ b_hh0,
    const float* __restrict__ w_ih, const float* __restrict__ w_hh,
    const float* __restrict__ b_ih, const float* __restrict__ b_hh,
    const float* __restrict__ w_lin, const float* __restrict__ b_lin,
    float* __restrict__ out, float* __restrict__ ws) {
  // counter area (first 4 KB of ws): arr[l] at cnt[l*64] (256 B apart),
  // garr at cnt[320], ggen at cnt[336]
  unsigned* cnt = (unsigned*)ws;
  float* data = ws + 1024;  // 4 KB offset
  float* h_ring = data;                          // LL*RING*HH
  float* h4 = h_ring + LL * RING * HH;           // TT*HH
  float* h4T = h4 + (size_t)TT * HH;             // HH*TT
  float* scores = h4T + (size_t)HH * TT;         // TT
  float* pbuf = scores + TT;                     // TT
  float* red = pbuf + TT;                        // 1

  const int b = blockIdx.x;
  const int tid = threadIdx.x;
  const int wv = tid >> 6;
  const int lane = tid & 63;
  const int l = b / BPL;
  const int q = b % BPL;
  const int j = q * WPB + wv;  // h-output index owned by this wave

  unsigned* arr_l = cnt + l * 64;
  unsigned* arr_lm1 = cnt + (l - 1) * 64;  // valid only when l > 0
  unsigned* arr_lp1 = cnt + (l + 1) * 64;  // valid only when l < LL-1
  unsigned* garr = cnt + 320;
  unsigned* ggen = cnt + 336;

  // ---- load weights, transposed so h-loads coalesce: w[g][m] pairs with
  // h[m*64 + lane] ----
  float whh[4][8], wih[4][8], bias[4];
  const float* WHH = (l == 0) ? w_hh0 : (w_hh + (size_t)(l - 1) * 4 * HH * HH);
#pragma unroll
  for (int g = 0; g < 4; ++g) {
    const int row = g * HH + j;
#pragma unroll
    for (int m = 0; m < 8; ++m) whh[g][m] = WHH[(size_t)row * HH + m * 64 + lane];
  }
  if (l == 0) {
#pragma unroll
    for (int g = 0; g < 4; ++g) {
      const int row = g * HH + j;
      wih[g][0] = w_ih0[(size_t)row * II + lane];
#pragma unroll
      for (int m = 1; m < 8; ++m) wih[g][m] = 0.0f;
      bias[g] = b_ih0[row] + b_hh0[row];
    }
  } else {
    const float* WIH = w_ih + (size_t)(l - 1) * 4 * HH * HH;
    const float* BIH = b_ih + (size_t)(l - 1) * 4 * HH;
    const float* BHH = b_hh + (size_t)(l - 1) * 4 * HH;
#pragma unroll
    for (int g = 0; g < 4; ++g) {
      const int row = g * HH + j;
#pragma unroll
      for (int m = 0; m < 8; ++m) wih[g][m] = WIH[(size_t)row * HH + m * 64 + lane];
      bias[g] = BIH[row] + BHH[row];
    }
  }
  // pin in VGPRs: opaque asm defeats load-rematerialization inside the loop
#pragma unroll
  for (int g = 0; g < 4; ++g) {
#pragma unroll
    for (int m = 0; m < 8; ++m) {
      asm volatile("" : "+v"(whh[g][m]));
      asm volatile("" : "+v"(wih[g][m]));
    }
    asm volatile("" : "+v"(bias[g]));
  }

  const float* own_rd = h_ring + (size_t)l * RING * HH + lane;
  const float* prev_rd = h_ring + (size_t)(l - 1) * RING * HH + lane;
  float* own_wr = h_ring + (size_t)l * RING * HH + j;

  float c = 0.0f;

  // ---- recurrence: fence-free, coherent-atomic h exchange ----
  for (int t = 0; t < TT; ++t) {
    // three wait conditions polled in parallel by three waves
    if (tid == 0 && t > 0) wait_ge(arr_l, (unsigned)(BPL * t));               // own h_{t-1}
    if (tid == 64 && l > 0) wait_ge(arr_lm1, (unsigned)(BPL * (t + 1)));      // input ready
    if (tid == 128 && l < LL - 1 && t >= RING)
      wait_ge(arr_lp1, (unsigned)(BPL * (t - RING + 1)));                     // ring slot free
    __syncthreads();

    float hp[8];
    if (t > 0) {
      const float* rp = own_rd + (size_t)((t - 1) & (RING - 1)) * HH;
#pragma unroll
      for (int m = 0; m < 8; ++m) hp[m] = ld_coh(rp + m * 64);
    } else {
#pragma unroll
      for (int m = 0; m < 8; ++m) hp[m] = 0.0f;
    }
    float xin[8];
    if (l == 0) {
      xin[0] = x[(size_t)t * II + lane];
#pragma unroll
      for (int m = 1; m < 8; ++m) xin[m] = 0.0f;
    } else {
      const float* rp = prev_rd + (size_t)(t & (RING - 1)) * HH;
#pragma unroll
      for (int m = 0; m < 8; ++m) xin[m] = ld_coh(rp + m * 64);
    }

    float ai = 0.0f, af = 0.0f, ag = 0.0f, ao = 0.0f;
#pragma unroll
    for (int m = 0; m < 8; ++m) {
      ai = fmaf(whh[0][m], hp[m], ai);
      af = fmaf(whh[1][m], hp[m], af);
      ag = fmaf(whh[2][m], hp[m], ag);
      ao = fmaf(whh[3][m], hp[m], ao);
    }
#pragma unroll
    for (int m = 0; m < 8; ++m) {
      ai = fmaf(wih[0][m], xin[m], ai);
      af = fmaf(wih[1][m], xin[m], af);
      ag = fmaf(wih[2][m], xin[m], ag);
      ao = fmaf(wih[3][m], xin[m], ao);
    }
    ai = wave_sum(ai); af = wave_sum(af); ag = wave_sum(ag); ao = wave_sum(ao);
    float gi = sigmoidf_(ai + bias[0]);
    float gf = sigmoidf_(af + bias[1]);
    float gg = tanhf(ag + bias[2]);
    float go = sigmoidf_(ao + bias[3]);
    c = gf * c + gi * gg;
    float h = go * tanhf(c);
    if (lane == 0) {
      st_coh(own_wr + (size_t)(t & (RING - 1)) * HH, h);
      if (l == LL - 1) {
        h4[(size_t)t * HH + j] = h;
        h4T[(size_t)j * TT + t] = h;
      }
    }
    // drain own store (sc-coherent store completed => globally visible)
    asm volatile("s_waitcnt vmcnt(0)" ::: "memory");
    __syncthreads();
    if (tid == 0) {
      __hip_atomic_fetch_add(arr_l, 1u, __ATOMIC_RELAXED, __HIP_MEMORY_SCOPE_AGENT);
    }
  }

  grid_barrier(garr, ggen, 0u);

  // ---- phase A: scores[t] = tanh(h4[t] . w_lin + b_lin) ----
  {
    const int gw = b * WPB + wv;
    if (gw < TT) {
      const int t = gw;
      const float4* hp4 = (const float4*)(h4 + (size_t)t * HH + lane * 8);
      const float4* wl4 = (const float4*)(w_lin + lane * 8);
      float4 a = hp4[0], d = hp4[1], wa = wl4[0], wd = wl4[1];
      float acc = 0.0f;
      acc = fmaf(a.x, wa.x, acc); acc = fmaf(a.y, wa.y, acc);
      acc = fmaf(a.z, wa.z, acc); acc = fmaf(a.w, wa.w, acc);
      acc = fmaf(d.x, wd.x, acc); acc = fmaf(d.y, wd.y, acc);
      acc = fmaf(d.z, wd.z, acc); acc = fmaf(d.w, wd.w, acc);
      acc = wave_sum(acc);
      float sc = tanhf(acc + b_lin[0]);
      if (lane == 0) scores[t] = sc;
    }
  }
  grid_barrier(garr, ggen, 1u);

  // ---- phase B: softmax over time (block 0 only) ----
  __shared__ float sbuf[20];
  if (b == 0) {
    float s0 = scores[tid];
    float s1 = scores[tid + 1024];
    float m = fmaxf(s0, s1);
    m = wave_max(m);
    if (lane == 0) sbuf[wv] = m;
    __syncthreads();
    if (tid == 0) {
      float M = sbuf[0];
      for (int k = 1; k < 16; ++k) M = fmaxf(M, sbuf[k]);
      sbuf[16] = M;
    }
    __syncthreads();
    float M = sbuf[16];
    float p0 = expf(s0 - M), p1 = expf(s1 - M);
    pbuf[tid] = p0;
    pbuf[tid + 1024] = p1;
    float ssum = wave_sum(p0 + p1);
    __syncthreads();
    if (lane == 0) sbuf[wv] = ssum;
    __syncthreads();
    if (tid == 0) {
      float S = 0.0f;
      for (int k = 0; k < 16; ++k) S += sbuf[k];
      red[0] = 1.0f / ((float)TT * S);
    }
  }
  grid_barrier(garr, ggen, 2u);

  // ---- phase C: out[j] = scale * sum_t p_t * h4T[j][t] ----
  {
    const int gw = b * WPB + wv;
    if (gw < HH) {
      const int jj = gw;
      const float scale = red[0];
      const float* hr = h4T + (size_t)jj * TT + lane * 32;
      const float* pr = pbuf + lane * 32;
      float acc = 0.0f;
#pragma unroll
      for (int m = 0; m < 32; ++m) acc = fmaf(hr[m], pr[m], acc);
      acc = wave_sum(acc);
      if (lane == 0) out[jj] = scale * acc;
    }
  }
}

extern "C" void kernel_launch(void* const* d_in, const int* in_sizes, int n_in,
                              void* d_out, int out_size, void* d_ws, size_t ws_size,
                              hipStream_t stream) {
  hipMemsetAsync(d_ws, 0, 4096, stream);  // zero all sync counters
  lstm_pipe<<<dim3(NBLK), dim3(1024), 0, stream>>>(
      (const float*)d_in[0],
      (const float*)d_in[1], (const float*)d_in[2],
      (const float*)d_in[3], (const float*)d_in[4],
      (const float*)d_in[5], (const float*)d_in[6],
      (const float*)d_in[7], (const float*)d_in[8],
      (const float*)d_in[9], (const float*)d_in[10],
      (float*)d_out, (float*)d_ws);
}